// Round 3
// baseline (386.682 us; speedup 1.0000x reference)
//
#include <hip/hip_runtime.h>

#define IN_DIM 1024
#define N_NEURONS 1024
#define N_SOMA 16384
#define BT 64          // batch tile (row = 64 f16 = 128 B)
#define NB 4096        // batch size

typedef _Float16 h8 __attribute__((ext_vector_type(8)));

__device__ __forceinline__ float leaky(float v) { return v >= 0.0f ? v : 0.1f * v; }

// ---- K0: transpose x [B][F] f32 -> xt tiled [bt][f][64] f16, chunk-swizzled ----
// 16-B batch-chunk c of feature row f is stored at slot c ^ (f&7) within the row.
__global__ void transpose_kernel(const float* __restrict__ x,
                                 _Float16* __restrict__ xt) {
  const int f = blockIdx.x * 256 + threadIdx.x;
  const int bt = blockIdx.y;
  const int b0 = bt * BT;
  h8* dst = (h8*)xt + ((size_t)bt * IN_DIM + f) * 8;
  const int r = f & 7;
#pragma unroll
  for (int o = 0; o < 8; ++o) {
    h8 v;
#pragma unroll
    for (int e = 0; e < 8; ++e)
      v[e] = (_Float16)x[(size_t)(b0 + o * 8 + e) * IN_DIM + f];
    dst[o ^ r] = v;  // swizzled slot
  }
}

// ---- K1: compact sparse dendrite weights ----
// pairs[s*32+p] = { f32 bits of w, (f<<7) | ((f&7)<<4) }  (swizzle-ready offset)
__global__ void compact_kernel(const float* __restrict__ Wd,
                               const float* __restrict__ mask,
                               uint2* __restrict__ pairs) {
  const int lane = threadIdx.x & 63;
  const int s = (blockIdx.x << 2) + (threadIdx.x >> 6);
  const float* mrow = mask + (size_t)s * IN_DIM + lane * 16;
  const float* wrow = Wd + (size_t)s * IN_DIM + lane * 16;
  float m[16], w[16];
#pragma unroll
  for (int k = 0; k < 4; ++k) {
    *(float4*)(m + 4 * k) = *(const float4*)(mrow + 4 * k);
    *(float4*)(w + 4 * k) = *(const float4*)(wrow + 4 * k);
  }
  int c = 0;
#pragma unroll
  for (int k = 0; k < 16; ++k) c += (m[k] != 0.0f) ? 1 : 0;
  int inc = c;
#pragma unroll
  for (int d = 1; d < 64; d <<= 1) {
    int t = __shfl_up(inc, d);
    if (lane >= d) inc += t;
  }
  int pos = inc - c;
  uint2* prow = pairs + ((size_t)s << 5);
#pragma unroll
  for (int k = 0; k < 16; ++k) {
    if (m[k] != 0.0f) {
      if (pos < 32) {
        const unsigned f = (unsigned)(lane * 16 + k);
        prow[pos] = make_uint2(__float_as_uint(w[k] * m[k]),
                               (f << 7) | ((f & 7) << 4));
      }
      ++pos;
    }
  }
}

// ---- K2: fused sparse-dendrite + block-diagonal soma layer ----
// grid (8, 64): x = 128-neuron tile, y = 64-batch tile. 1024 thr = 16 waves.
// Lane = n*8+j: neuron n (8/wave), batch-oct j. addr = p.y ^ (j<<4) de-swizzles;
// per neuron-row all 8 j-lanes cover all 8 bank groups exactly once -> conflict-free.
__global__ __launch_bounds__(1024) void dendrite_kernel(
    const _Float16* __restrict__ xt, const uint2* __restrict__ pairs,
    const float* __restrict__ bd, const float* __restrict__ Ws,
    const float* __restrict__ bs, float* __restrict__ out) {
  __shared__ _Float16 xs[IN_DIM * BT];  // 128 KB
  const uint4* src = (const uint4*)(xt + (size_t)blockIdx.y * IN_DIM * BT);
  uint4* dst = (uint4*)xs;
  for (int q = threadIdx.x; q < IN_DIM * BT * 2 / 16; q += 1024) dst[q] = src[q];
  __syncthreads();

  const int lane = threadIdx.x & 63;
  const int wv = threadIdx.x >> 6;
  const int n = lane >> 3;
  const int j = lane & 7;
  const int i = blockIdx.x * 128 + wv * 8 + n;  // neuron id
  const unsigned jj = (unsigned)j << 4;
  const char* xb = (const char*)xs;

  float p[8] = {0.f, 0.f, 0.f, 0.f, 0.f, 0.f, 0.f, 0.f};
  const float* wsrow = Ws + (size_t)i * N_SOMA + (i << 4);
  const float* bdrow = bd + (i << 4);

  for (int g = 0; g < 16; ++g) {
    const uint4* pr = (const uint4*)(pairs + (((size_t)(i << 4) + g) << 5));
    float a[8] = {0.f, 0.f, 0.f, 0.f, 0.f, 0.f, 0.f, 0.f};
#pragma unroll
    for (int k = 0; k < 16; ++k) {
      const uint4 p4 = pr[k];
      {
        const float w = __uint_as_float(p4.x);
        const h8 xv = *(const h8*)(xb + (p4.y ^ jj));
#pragma unroll
        for (int q = 0; q < 8; ++q) a[q] = fmaf((float)xv[q], w, a[q]);
      }
      {
        const float w = __uint_as_float(p4.z);
        const h8 xv = *(const h8*)(xb + (p4.w ^ jj));
#pragma unroll
        for (int q = 0; q < 8; ++q) a[q] = fmaf((float)xv[q], w, a[q]);
      }
    }
    const float bdv = bdrow[g];
    const float wsv = wsrow[g];
#pragma unroll
    for (int q = 0; q < 8; ++q) p[q] = fmaf(leaky(a[q] + bdv), wsv, p[q]);
  }
  const float bsv = bs[i];
  const int b0 = blockIdx.y * BT + j * 8;
#pragma unroll
  for (int q = 0; q < 8; ++q)
    out[(size_t)(b0 + q) * N_NEURONS + i] = leaky(p[q] + bsv);
}

extern "C" void kernel_launch(void* const* d_in, const int* in_sizes, int n_in,
                              void* d_out, int out_size, void* d_ws, size_t ws_size,
                              hipStream_t stream) {
  const float* x = (const float*)d_in[0];
  const float* Wd = (const float*)d_in[1];
  const float* bd = (const float*)d_in[2];
  const float* Ws = (const float*)d_in[3];
  const float* bs = (const float*)d_in[4];
  const float* dmask = (const float*)d_in[5];
  float* out = (float*)d_out;

  uint2* pairs = (uint2*)d_ws;                          // 4 MB
  _Float16* xt = (_Float16*)((char*)d_ws + (4 << 20));  // 8 MB

  transpose_kernel<<<dim3(4, NB / BT), dim3(256), 0, stream>>>(x, xt);
  compact_kernel<<<dim3(N_SOMA / 4), dim3(256), 0, stream>>>(Wd, dmask, pairs);
  dendrite_kernel<<<dim3(N_NEURONS / 128, NB / BT), dim3(1024), 0, stream>>>(
      xt, pairs, bd, Ws, bs, out);
}